// Round 5
// baseline (1113.443 us; speedup 1.0000x reference)
//
#include <hip/hip_runtime.h>

#define E_EXP 8
#define D_IN 1024
#define D_H 4096
#define D_OUT 1024
#define N_TOK 4096

using f32x4  = __attribute__((ext_vector_type(4))) float;
using bf16x8 = __attribute__((ext_vector_type(8))) __bf16;
using us8    = __attribute__((ext_vector_type(8))) unsigned short;

typedef __attribute__((address_space(1))) void gvoid_t;
typedef __attribute__((address_space(3))) void lvoid_t;

// async global->LDS, 16B per lane; LDS dest is wave-uniform base + lane*16
__device__ __forceinline__ void async_load16(const void* g, void* l) {
    __builtin_amdgcn_global_load_lds((gvoid_t*)g, (lvoid_t*)l, 16, 0, 0);
}

__device__ __forceinline__ unsigned short f2bf(float f) {
    unsigned int x = __float_as_uint(f);
    x += 0x7fffu + ((x >> 16) & 1u);   // round-to-nearest-even
    return (unsigned short)(x >> 16);
}

// ---------------- cast x fp32 -> bf16 ----------------
__global__ __launch_bounds__(256) void cast_x_kernel(const float* __restrict__ in,
                                                     unsigned short* __restrict__ outp) {
    int i = blockIdx.x * 256 + threadIdx.x;
    float4 f0 = ((const float4*)in)[i * 2];
    float4 f1 = ((const float4*)in)[i * 2 + 1];
    us8 u;
    u[0] = f2bf(f0.x); u[1] = f2bf(f0.y); u[2] = f2bf(f0.z); u[3] = f2bf(f0.w);
    u[4] = f2bf(f1.x); u[5] = f2bf(f1.y); u[6] = f2bf(f1.z); u[7] = f2bf(f1.w);
    ((us8*)outp)[i] = u;
}

// ---------------- gate: softmax(x @ Wg + bg) over E=8, fp32 ----------------
__global__ __launch_bounds__(256) void gate_kernel(const float* __restrict__ x,
                                                   const float* __restrict__ Wg,
                                                   const float* __restrict__ bg,
                                                   float* __restrict__ gate) {
    int wave = threadIdx.x >> 6, lane = threadIdx.x & 63;
    int n = blockIdx.x * 4 + wave;
    int e = lane & 7, part = lane >> 3;                 // 8 experts x 8 K-parts
    const float* xr = x + (size_t)n * D_IN + part * (D_IN / 8);
    const float* wr = Wg + (size_t)part * (D_IN / 8) * E_EXP + e;
    float s = 0.f;
#pragma unroll 4
    for (int d = 0; d < D_IN / 8; d++) s += xr[d] * wr[d * E_EXP];
    s += __shfl_xor(s, 8);
    s += __shfl_xor(s, 16);
    s += __shfl_xor(s, 32);                              // full dot per expert
    s += bg[e];
    float m = s;
    m = fmaxf(m, __shfl_xor(m, 1));
    m = fmaxf(m, __shfl_xor(m, 2));
    m = fmaxf(m, __shfl_xor(m, 4));
    float ex = __expf(s - m);
    float sum = ex;
    sum += __shfl_xor(sum, 1);
    sum += __shfl_xor(sum, 2);
    sum += __shfl_xor(sum, 4);
    if (lane < 8) gate[n * 8 + lane] = ex / sum;
}

// ---------------- transpose+cast 64x64: in fp32 [z][R][C] -> out bf16 [z][C][R] ----------------
__global__ __launch_bounds__(256) void transpose_cast64(const float* __restrict__ in,
                                                        unsigned short* __restrict__ outp,
                                                        int R, int C) {
    in   += (size_t)blockIdx.z * R * C;
    outp += (size_t)blockIdx.z * R * C;
    __shared__ float tile[64][65];
    const int t = threadIdx.x;
    const int r0 = blockIdx.y * 64, c0 = blockIdx.x * 64;
    // load: 4 passes, float4 per thread
    {
        int r = t >> 4, cc = (t & 15) * 4;
#pragma unroll
        for (int p = 0; p < 4; p++) {
            float4 v = *(const float4*)(in + (size_t)(r0 + p * 16 + r) * C + c0 + cc);
            tile[p * 16 + r][cc]     = v.x;
            tile[p * 16 + r][cc + 1] = v.y;
            tile[p * 16 + r][cc + 2] = v.z;
            tile[p * 16 + r][cc + 3] = v.w;
        }
    }
    __syncthreads();
    // write: 2 passes, ushort8 per thread
    {
        int c = t >> 3, w = t & 7;
#pragma unroll
        for (int p = 0; p < 2; p++) {
            int cc = p * 32 + c;
            us8 v;
#pragma unroll
            for (int i = 0; i < 8; i++) v[i] = f2bf(tile[w * 8 + i][cc]);
            *(us8*)(outp + (size_t)(c0 + cc) * R + r0 + w * 8) = v;
        }
    }
}

// ---------------- out init: out[n][o] = sum_e gate[n,e]*b2[e,o] ----------------
__global__ __launch_bounds__(256) void out_init_kernel(const float* __restrict__ gate,
                                                       const float* __restrict__ b2,
                                                       float* __restrict__ out) {
    int i = blockIdx.x * 256 + threadIdx.x;          // one float4 of out
    int n = i / (D_OUT / 4), o4 = i % (D_OUT / 4);
    const float* g = gate + n * 8;
    float4 s = make_float4(0.f, 0.f, 0.f, 0.f);
#pragma unroll
    for (int e = 0; e < E_EXP; e++) {
        float4 b = ((const float4*)(b2 + (size_t)e * D_OUT))[o4];
        float ge = g[e];
        s.x += ge * b.x; s.y += ge * b.y; s.z += ge * b.z; s.w += ge * b.w;
    }
    ((float4*)out)[i] = s;
}

// ---------------- bf16 MFMA GEMM, 256x128 block tile, 128x64 wave tile ----------------
// BK=32, double-buffered LDS, ONE barrier per K-iter: prefetch for iter i+1 is
// issued right after barrier i, so barrier i+1's vmcnt(0) drain finds it already
// landed (aged one full compute phase). LDS rows = 64 B = 4 chunks of 16 B,
// swizzle phys_chunk = quad ^ (row & 3) -> conflict-free b128 reads.
// MODE 0 (layer1): A=xb [N_TOK][D_IN], B=W1T[e][h][k], K=1024; writes
//                  h[er*hstride + row*D_H + col] = bf16(gate[row,e]*relu(acc + b1[e,col]))
// MODE 1 (layer2): A=h+er*hstride [N_TOK][D_H], B=W2T[e][o][h], K=4096;
//                  unsafeAtomicAdd(out[row*D_OUT + col], acc)
// 1-D grid, XCD-partitioned m-tiles, col-tile fastest, expert slowest.
template <int MODE>
__global__ __launch_bounds__(256, 2) void gemm_kernel(const unsigned short* __restrict__ Abase,
                                                      const unsigned short* __restrict__ Wbase,
                                                      const float* __restrict__ b1a,
                                                      const float* __restrict__ gate,
                                                      unsigned short* __restrict__ Hout,
                                                      float* __restrict__ out,
                                                      int e0, size_t hstride) {
    __shared__ __align__(16) unsigned short As[2][256 * 32];   // 2 x 16 KiB
    __shared__ __align__(16) unsigned short Bs[2][128 * 32];   // 2 x  8 KiB
    const int t = threadIdx.x;
    const int wave = t >> 6;
    const int lane = t & 63;
    const int quad = lane >> 4;
    const int l16 = lane & 15;

    const int lin = blockIdx.x;
    const int xcd = lin & 7;
    const int s = lin >> 3;
    int n_t, er, m_t;
    if (MODE == 0) {                 // 2048 blocks: s in [0,256)
        n_t = s & 31;                // 32 col-tiles of 128 (fastest: share A-tile)
        int em = s >> 5;             // [0,8)
        er = em >> 1;                // expert slowest
        m_t = (em & 1) + xcd * 2;    // 16 m-tiles of 256
    } else {                         // 512 blocks: s in [0,64)
        n_t = s & 7;                 // 8 col-tiles of 128
        int em = s >> 3;             // [0,8)
        er = em >> 1;
        m_t = (em & 1) + xcd * 2;
    }
    const int e = e0 + er;
    const int n0 = n_t * 128;
    const int m0 = m_t * 256;
    const int ld = (MODE == 0) ? D_IN : D_H;
    const int K  = (MODE == 0) ? D_IN : D_H;

    const unsigned short* A = Abase + (MODE == 1 ? (size_t)er * hstride : (size_t)0);
    const unsigned short* B = Wbase + (size_t)e * 4194304;   // 4M elems per expert slice

    // staging: A tile = 1024 phys chunks (t + j*256, j=0..3), B = 512 (j=0..1).
    // phys p: row = p>>2, cph = p&3; global logical chunk c = cph ^ (row&3).
    const int r0 = t >> 2;                       // [0,64); rows r0 + 64*j
    const int gk = ((t & 3) ^ (r0 & 3)) << 3;    // same for all j (64 % 4 == 0)
    const unsigned short* aP = A + (size_t)(m0 + r0) * ld + gk;
    const unsigned short* bP = B + (size_t)(n0 + r0) * ld + gk;
    const int ldsOff = wave * 64 * 8;            // per-wave contiguous 64x16B slot

    const int wm = (wave & 1) * 128;
    const int wn = (wave >> 1) * 64;
    f32x4 acc[8][4] = {};

    const int NIT = K / 32;
    // prologue: stage tile 0 into buffer 0
#pragma unroll
    for (int j = 0; j < 4; j++)
        async_load16(aP + (size_t)(j * 64) * ld, &As[0][j * 2048 + ldsOff]);
#pragma unroll
    for (int j = 0; j < 2; j++)
        async_load16(bP + (size_t)(j * 64) * ld, &Bs[0][j * 2048 + ldsOff]);

    for (int it = 0; it < NIT; ++it) {
        __syncthreads();   // drains the prefetch targeting THIS iter's buffer (aged 1 iter)
        if (it + 1 < NIT) {
            const int kn = (it + 1) * 32;
            const int pb = (it + 1) & 1;
#pragma unroll
            for (int j = 0; j < 4; j++)
                async_load16(aP + kn + (size_t)(j * 64) * ld, &As[pb][j * 2048 + ldsOff]);
#pragma unroll
            for (int j = 0; j < 2; j++)
                async_load16(bP + kn + (size_t)(j * 64) * ld, &Bs[pb][j * 2048 + ldsOff]);
        }
        const unsigned short* Ar = As[it & 1];
        const unsigned short* Br = Bs[it & 1];
        bf16x8 af[8], bfr[4];
#pragma unroll
        for (int i = 0; i < 8; i++) {
            int row = wm + i * 16 + l16;
            af[i] = *reinterpret_cast<const bf16x8*>(&Ar[row * 32 + ((quad ^ (row & 3)) * 8)]);
        }
#pragma unroll
        for (int j = 0; j < 4; j++) {
            int row = wn + j * 16 + l16;
            bfr[j] = *reinterpret_cast<const bf16x8*>(&Br[row * 32 + ((quad ^ (row & 3)) * 8)]);
        }
#pragma unroll
        for (int i = 0; i < 8; i++)
#pragma unroll
            for (int j = 0; j < 4; j++)
                acc[i][j] = __builtin_amdgcn_mfma_f32_16x16x32_bf16(af[i], bfr[j], acc[i][j], 0, 0, 0);
    }

    // C/D layout: col = lane&15, row = quad*4 + reg   [verified m89/m91]
    const int mrow = m0 + wm + quad * 4;
    const int ncol = n0 + wn + l16;
    if (MODE == 0) {
        const float* bias = b1a + (size_t)e * D_H;
        unsigned short* Hbase = Hout + (size_t)er * hstride;
#pragma unroll
        for (int i = 0; i < 8; i++) {
#pragma unroll
            for (int r = 0; r < 4; r++) {
                int row = mrow + i * 16 + r;
                float g = gate[row * 8 + e];
                unsigned short* hr = Hbase + (size_t)row * D_H;
#pragma unroll
                for (int j = 0; j < 4; j++) {
                    int col = ncol + j * 16;
                    float v = fmaxf(acc[i][j][r] + bias[col], 0.f) * g;
                    hr[col] = f2bf(v);
                }
            }
        }
    } else {
#pragma unroll
        for (int i = 0; i < 8; i++) {
#pragma unroll
            for (int r = 0; r < 4; r++) {
                int row = mrow + i * 16 + r;
                float* orow = out + (size_t)row * D_OUT;
#pragma unroll
                for (int j = 0; j < 4; j++) {
                    int col = ncol + j * 16;
                    unsafeAtomicAdd(&orow[col], acc[i][j][r]);
                }
            }
        }
    }
}

extern "C" void kernel_launch(void* const* d_in, const int* in_sizes, int n_in,
                              void* d_out, int out_size, void* d_ws, size_t ws_size,
                              hipStream_t stream) {
    const float* x  = (const float*)d_in[0];
    const float* W1 = (const float*)d_in[1];
    const float* b1 = (const float*)d_in[2];
    const float* W2 = (const float*)d_in[3];
    const float* b2 = (const float*)d_in[4];
    const float* Wg = (const float*)d_in[5];
    const float* bg = (const float*)d_in[6];
    float* out = (float*)d_out;

    // workspace layout (~264 MiB)
    char* p = (char*)d_ws;
    unsigned short* xb  = (unsigned short*)p; p += (size_t)N_TOK * D_IN * 2;        //   8 MiB
    unsigned short* W1T = (unsigned short*)p; p += (size_t)E_EXP * D_IN * D_H * 2;  //  64 MiB [e][h][k]
    unsigned short* W2T = (unsigned short*)p; p += (size_t)E_EXP * D_H * D_OUT * 2; //  64 MiB [e][o][h]
    float* gate         = (float*)p;          p += (size_t)N_TOK * E_EXP * 4;       // 128 KiB
    unsigned short* h   = (unsigned short*)p;                                       // 128 MiB (4 experts)

    const size_t hstride = (size_t)N_TOK * D_H;   // per-expert h' slice (32 MiB)

    cast_x_kernel<<<dim3(N_TOK * D_IN / 2048), 256, 0, stream>>>(x, xb);
    gate_kernel<<<dim3(N_TOK / 4), 256, 0, stream>>>(x, Wg, bg, gate);
    // W1 [e][1024][4096] -> W1T [e][4096][1024]
    transpose_cast64<<<dim3(D_H / 64, D_IN / 64, E_EXP), 256, 0, stream>>>(W1, W1T, D_IN, D_H);
    // W2 [e][4096][1024] -> W2T [e][1024][4096]
    transpose_cast64<<<dim3(D_OUT / 64, D_H / 64, E_EXP), 256, 0, stream>>>(W2, W2T, D_H, D_OUT);
    // out = sum_e gate*b2 (GEMM2 atomically accumulates on top)
    out_init_kernel<<<dim3(N_TOK * D_OUT / 1024), 256, 0, stream>>>(gate, b2, out);

    // two groups of 4 experts: h' (128 MiB) stays L3-resident between the pair
    for (int g = 0; g < 2; g++) {
        gemm_kernel<0><<<dim3(2048), 256, 0, stream>>>(
            xb, W1T, b1, gate, h, nullptr, g * 4, hstride);
        gemm_kernel<1><<<dim3(512), 256, 0, stream>>>(
            h, W2T, nullptr, nullptr, nullptr, out, g * 4, hstride);
    }
}